// Round 10
// baseline (325.856 us; speedup 1.0000x reference)
//
#include <hip/hip_runtime.h>
#include <stdint.h>

// GAT layer on MI355X: B=8, N=2048, F=128.
// h = x@W^T ; s1=h@a1 ; s2=h@a2 ; e=leaky(s1[i]+s2[j]); masked softmax; out=attn@h
// Scores rank-1. R10: adj (134 MB int32) -> 4 MB bitmask in a streaming pack
// pass fused into the pre-kernel; attn reads bits (L2-resident) instead of
// streaming adj -> attn HBM demand is just the 67 MB out write.
//
// K_pre (gat_pre, 1280 blocks):
//   blocks 0..255: gat_h body — W fp32->bf16 swizzled LDS, x tile coalesced
//     LDS, split-precision x(hi+lo) MFMA, chunked hT (HC64 swizzle in global
//     layout) + s1/s2. Unchanged from R9.
//   blocks 256..1279: adj pack — wave reads 64 ints coalesced, v_cmp mask
//     via __ballot, one uint64 store per 256 B read. BW-bound ~22 us,
//     co-scheduled with gat_h blocks.
// K2 (gat_attn): R9 structure (512 x 256, global_load_lds dbuf, b=bid&7,
//   jh/rh wave split, LDS combine) with bitmask instead of adj prefetch.

#define B_ 8
#define N_ 2048
#define FD 128
#define ALPHA_ 0.2f
#define TJ 64
#define NCHL 16                   // chunks per j-half (1024/64)
#define CHUNK_U4 1024             // 128 o x 8 u4 per 64-j chunk (16 KB)
#define PACKB 1024                // pack blocks (after 256 gat_h blocks)

typedef __attribute__((ext_vector_type(8))) short short8;
typedef __attribute__((ext_vector_type(4))) float f32x4;

// 4-bit XOR swizzle for the 128x128 W tile (16B-chunk units)
#define HCHUNK(o, jc) ((((o) * 16) + ((jc) ^ ((o) & 15))) * 8)  // ushort offset
// 3-bit XOR swizzle for 128x64 hT chunks (uint4 units)
#define HC64(o, jc) ((o) * 8 + ((jc) ^ ((o) & 7)))              // uint4 index

__device__ __forceinline__ float bf2f(unsigned short u) {
    union { uint32_t i; float f; } v; v.i = ((uint32_t)u) << 16; return v.f;
}
__device__ __forceinline__ unsigned short f2bf(float f) {
    union { float f; uint32_t i; } v; v.f = f;
    uint32_t x = v.i;
    uint32_t r = (x + 0x7fffu + ((x >> 16) & 1u)) >> 16;  // RNE
    return (unsigned short)r;
}

// async global->LDS, 16B/lane; LDS base wave-uniform, HW adds lane*16.
__device__ __forceinline__ void gl2lds16(const uint4* g, uint4* l) {
    __builtin_amdgcn_global_load_lds(
        (const __attribute__((address_space(1))) uint32_t*)g,
        (__attribute__((address_space(3))) uint32_t*)l, 16, 0, 0);
}

// ---------------------------------------------------------------------------
// Kernel 1 (merged): blocks 0..255 = h-GEMM; blocks 256..1279 = adj bit-pack.
// ---------------------------------------------------------------------------
__global__ __launch_bounds__(256) void gat_pre(
    const float* __restrict__ x,
    const float* __restrict__ W,
    const float* __restrict__ a,
    const int* __restrict__ adj,
    unsigned short* __restrict__ hT,   // chunked: [b][kc][HC64(o,jc)*8+(j&7)]
    float* __restrict__ s1o, float* __restrict__ s2o,
    unsigned long long* __restrict__ bits)  // [b][i][cj] cj=j/64, bit=j%64
{
    __shared__ __align__(16) unsigned short Wlds[FD * FD];  // 32KB, swizzled
    __shared__ __align__(16) uint4 xs[64][32];              // 32KB, c^(row&31)

    const int bid = blockIdx.x;
    const int tid = threadIdx.x;
    const int w = tid >> 6;
    const int lane = tid & 63;

    if (bid >= 256) {
        // ---- adj -> bitmask pack: wave wid handles 128 chunks of 64 j ----
        const int wid = (bid - 256) * 4 + w;          // 0..4095
        const int* base = adj + (size_t)wid * 8192;   // 128*64 ints
        unsigned long long* ob = bits + (size_t)wid * 128;
#pragma unroll 8
        for (int it = 0; it < 128; it++) {
            int v = base[it * 64 + lane];
            unsigned long long mask = __ballot(v > 0);
            if (lane == 0) ob[it] = mask;
        }
        return;
    }

    const int m = lane & 15;
    const int quad = lane >> 4;

    // ---- stage W (fp32 -> bf16) into swizzled LDS ----
#pragma unroll
    for (int it = 0; it < 8; it++) {
        int cid = it * 256 + tid;          // 2048 16B-chunks
        int o = cid >> 4, kc = cid & 15;
        const float* wp = W + (size_t)o * FD + kc * 8;
        float4 w0 = *(const float4*)wp;
        float4 w1 = *(const float4*)(wp + 4);
        uint4 pk;
        pk.x = (uint32_t)f2bf(w0.x) | ((uint32_t)f2bf(w0.y) << 16);
        pk.y = (uint32_t)f2bf(w0.z) | ((uint32_t)f2bf(w0.w) << 16);
        pk.z = (uint32_t)f2bf(w1.x) | ((uint32_t)f2bf(w1.y) << 16);
        pk.w = (uint32_t)f2bf(w1.z) | ((uint32_t)f2bf(w1.w) << 16);
        *(uint4*)&Wlds[HCHUNK(o, kc)] = pk;
    }
    // ---- stage x tile (64 rows x 128 f fp32 = 32 KB) coalesced ----
#pragma unroll
    for (int it = 0; it < 8; it++) {
        int idx = it * 256 + tid;          // 2048 uint4
        int row = idx >> 5, c = idx & 31;
        uint4 v = *(const uint4*)(x + (size_t)bid * 8192 + (size_t)idx * 4);
        xs[row][c ^ (row & 31)] = v;
    }
    __syncthreads();

    f32x4 acc[8];
#pragma unroll
    for (int ot = 0; ot < 8; ot++) acc[ot] = (f32x4){0.f, 0.f, 0.f, 0.f};

    const int xrow = w * 16 + m;
#pragma unroll
    for (int ks = 0; ks < 4; ks++) {
        const int c0 = ks * 8 + quad * 2;
        union { uint4 u[2]; float f[8]; } xv;
        xv.u[0] = xs[xrow][c0 ^ (xrow & 31)];
        xv.u[1] = xs[xrow][(c0 + 1) ^ (xrow & 31)];
        union { unsigned short us[8]; short8 v; } ahi, alo;
#pragma unroll
        for (int jj = 0; jj < 8; jj++) {
            unsigned short hi = f2bf(xv.f[jj]);
            ahi.us[jj] = hi;
            alo.us[jj] = f2bf(xv.f[jj] - bf2f(hi));
        }
#pragma unroll
        for (int ot = 0; ot < 8; ot++) {
            union { uint4 u; short8 v; } bw;
            bw.u = *(const uint4*)&Wlds[HCHUNK(ot * 16 + m, ks * 4 + quad)];
            acc[ot] = __builtin_amdgcn_mfma_f32_16x16x32_bf16(ahi.v, bw.v, acc[ot], 0, 0, 0);
            acc[ot] = __builtin_amdgcn_mfma_f32_16x16x32_bf16(alo.v, bw.v, acc[ot], 0, 0, 0);
        }
    }

    // Epilogue: store hT (chunked+swizzled, bf16) + s1/s2 partial reduce.
    const int rc0 = bid * 64 + w * 16 + quad * 4;  // C rows rc0..rc0+3 (= j)
    const int bb = rc0 >> 11;
    const int jb = rc0 & (N_ - 1);
    const int kc = jb >> 6;
    const int jcl = (jb & 63) >> 3;
    const int off = jb & 7;                        // 0 or 4
    unsigned short* hTb = hT + (size_t)bb * FD * N_ + (size_t)kc * (CHUNK_U4 * 8);
    float s1p[4] = {0.f, 0.f, 0.f, 0.f};
    float s2p[4] = {0.f, 0.f, 0.f, 0.f};
#pragma unroll
    for (int ot = 0; ot < 8; ot++) {
        const int o = ot * 16 + m;
        uint2 pk;
        pk.x = (uint32_t)f2bf(acc[ot][0]) | ((uint32_t)f2bf(acc[ot][1]) << 16);
        pk.y = (uint32_t)f2bf(acc[ot][2]) | ((uint32_t)f2bf(acc[ot][3]) << 16);
        *(uint2*)(hTb + (size_t)HC64(o, jcl) * 8 + off) = pk;
        float a1v = a[o], a2v = a[FD + o];
#pragma unroll
        for (int r = 0; r < 4; r++) {
            s1p[r] += acc[ot][r] * a1v;
            s2p[r] += acc[ot][r] * a2v;
        }
    }
#pragma unroll
    for (int offx = 8; offx >= 1; offx >>= 1) {
#pragma unroll
        for (int r = 0; r < 4; r++) {
            s1p[r] += __shfl_xor(s1p[r], offx);
            s2p[r] += __shfl_xor(s2p[r], offx);
        }
    }
    if (m == 0) {
#pragma unroll
        for (int r = 0; r < 4; r++) {
            s1o[rc0 + r] = s1p[r];
            s2o[rc0 + r] = s2p[r];
        }
    }
}

// ---------------------------------------------------------------------------
// Kernel 2: fused masked-softmax + PV (MFMA), bitmask edition.
// 512 blocks x 256 threads (4 waves), 2 blocks/CU. b = bid&7 (XCD-aligned),
// i0 = (bid>>3)*32. Wave w: jh=w>>1, rh=w&1: rows [i0+rh*16,+16),
// j [jh*1024,+1024). hT via global_load_lds dbuf; mask = 1 uint2/chunk (L1).
// ---------------------------------------------------------------------------
__global__ __launch_bounds__(256, 2) void gat_attn(
    const unsigned long long* __restrict__ bits,
    const unsigned short* __restrict__ hT,
    const float* __restrict__ s1,
    const float* __restrict__ s2,
    float* __restrict__ out)
{
    __shared__ __align__(16) uint4 hbuf[2][2][CHUNK_U4];  // [jh][buf], 64 KB

    const int bid = blockIdx.x;
    const int b = bid & 7;
    const int i0 = (bid >> 3) * 32;
    const int tid = threadIdx.x;
    const int lane = tid & 63;
    const int w = tid >> 6;
    const int jh = w >> 1;
    const int rh = w & 1;
    const int m = lane & 15;
    const int quad = lane >> 4;

    const int irow = i0 + rh * 16 + m;     // this lane's P row (A-frag m)
    const float s1v = s1[b * N_ + irow];
    const uint2* bitrow = (const uint2*)(bits + ((size_t)(b * N_ + irow)) * 32
                                         + jh * NCHL);
    const uint4* hTc = (const uint4*)(hT + (size_t)b * FD * N_)
                       + (size_t)jh * NCHL * CHUNK_U4;
    const float* s2b = s2 + b * N_ + jh * 1024;

    // ---- prologue: async-stage chunk 0; prefetch s2 for k=0 ----
#pragma unroll
    for (int it = 0; it < 8; it++)
        gl2lds16(&hTc[it * 128 + rh * 64 + lane], &hbuf[jh][0][it * 128 + rh * 64]);
    float4 scur[4];
#pragma unroll
    for (int ks = 0; ks < 2; ks++) {
        scur[2 * ks]     = *(const float4*)(s2b + ks * 32 + quad * 8);
        scur[2 * ks + 1] = *(const float4*)(s2b + ks * 32 + quad * 8 + 4);
    }
    __syncthreads();

    f32x4 acc[8];
#pragma unroll
    for (int ot = 0; ot < 8; ot++) acc[ot] = (f32x4){0.f, 0.f, 0.f, 0.f};
    float rs_loc = 0.f;

    for (int k = 0; k < NCHL; k++) {
        const int buf = k & 1;
        const bool more = (k + 1 < NCHL);
        float4 snext[4];
        if (more) {
            // async-stage chunk k+1 (in flight across compute; barrier drains)
#pragma unroll
            for (int it = 0; it < 8; it++)
                gl2lds16(&hTc[(size_t)(k + 1) * CHUNK_U4 + it * 128 + rh * 64 + lane],
                         &hbuf[jh][buf ^ 1][it * 128 + rh * 64]);
            const int j1 = (k + 1) * TJ;
#pragma unroll
            for (int ks = 0; ks < 2; ks++) {
                snext[2 * ks]     = *(const float4*)(s2b + j1 + ks * 32 + quad * 8);
                snext[2 * ks + 1] = *(const float4*)(s2b + j1 + ks * 32 + quad * 8 + 4);
            }
        }

        // ---- compute chunk k; mask bits: chunk uint64, bit = ks*32+quad*8+jj
        const uint2 bm = bitrow[k];
#pragma unroll
        for (int ks = 0; ks < 2; ks++) {
            float4 sa = scur[2 * ks], sb = scur[2 * ks + 1];
            float sarr[8] = {sa.x, sa.y, sa.z, sa.w, sb.x, sb.y, sb.z, sb.w};
            const uint32_t byte = ((ks ? bm.y : bm.x) >> (quad * 8)) & 0xffu;
            union { unsigned short us[8]; short8 v; } af;
#pragma unroll
            for (int jj = 0; jj < 8; jj++) {
                float e = s1v + sarr[jj];
                e = (e > 0.f) ? e : (ALPHA_ * e);
                float p = ((byte >> jj) & 1u) ? __expf(e) : 0.f;
                rs_loc += p;
                af.us[jj] = f2bf(p);
            }
            const int jc = ks * 4 + quad;  // B-frag 16B-chunk index
#pragma unroll
            for (int ot = 0; ot < 8; ot++) {
                const int o = ot * 16 + m;  // B-frag n = lane&15
                union { uint4 u; short8 v; } bf;
                bf.u = *(const uint4*)&hbuf[jh][buf][HC64(o, jc)];
                acc[ot] = __builtin_amdgcn_mfma_f32_16x16x32_bf16(af.v, bf.v, acc[ot], 0, 0, 0);
            }
        }

        __syncthreads();  // drains vmcnt(0): chunk k+1 staged; safe to flip
        if (more) {
#pragma unroll
            for (int q = 0; q < 4; q++) scur[q] = snext[q];
        }
    }

    // ---- cross-j-half combine via LDS (reuse hbuf; last barrier above) ----
    float* xch = (float*)&hbuf[0][0][0];   // 16 KB acc + 128 B rowsums
    rs_loc += __shfl_xor(rs_loc, 16);      // all lanes: sum for row m
    rs_loc += __shfl_xor(rs_loc, 32);
    if (jh == 1) {
#pragma unroll
        for (int ot = 0; ot < 8; ot++)
#pragma unroll
            for (int r = 0; r < 4; r++)
                xch[rh * 2048 + (quad * 4 + r) * 128 + ot * 16 + m] = acc[ot][r];
        if (quad == 0) xch[4096 + rh * 16 + m] = rs_loc;
    }
    __syncthreads();
    if (jh == 0) {
        float rinv[4];
#pragma unroll
        for (int r = 0; r < 4; r++) {
            const int p = quad * 4 + r;
            rinv[r] = 1.0f / (__shfl(rs_loc, p) + xch[4096 + rh * 16 + p]);
        }
        float* outp = out + (size_t)(b * N_ + i0 + rh * 16) * FD;
#pragma unroll
        for (int ot = 0; ot < 8; ot++) {
            const int col = ot * 16 + m;
#pragma unroll
            for (int r = 0; r < 4; r++) {
                float v = acc[ot][r] + xch[rh * 2048 + (quad * 4 + r) * 128 + col];
                outp[(size_t)(quad * 4 + r) * FD + col] = v * rinv[r];
            }
        }
    }
}

// ---------------------------------------------------------------------------
extern "C" void kernel_launch(void* const* d_in, const int* in_sizes, int n_in,
                              void* d_out, int out_size, void* d_ws, size_t ws_size,
                              hipStream_t stream) {
    const void* xv = d_in[0];
    const void* adjv = d_in[1];
    const void* Wv = d_in[2];
    const void* av = d_in[3];
    for (int i = 0; i < n_in; i++) {
        switch (in_sizes[i]) {
            case 2097152:  xv = d_in[i]; break;
            case 33554432: adjv = d_in[i]; break;
            case 16384:    Wv = d_in[i]; break;
            case 256:      av = d_in[i]; break;
            default: break;
        }
    }
    const float* x = (const float*)xv;
    const int* adj = (const int*)adjv;
    const float* W = (const float*)Wv;
    const float* a = (const float*)av;
    float* out = (float*)d_out;

    // ws: hT 4MB | s1 64KB | s2 64KB | bits 4MB
    char* p = (char*)d_ws;
    unsigned short* hT = (unsigned short*)p;       p += (size_t)B_ * FD * N_ * 2;
    float* s1 = (float*)p;                         p += (size_t)B_ * N_ * 4;
    float* s2 = (float*)p;                         p += (size_t)B_ * N_ * 4;
    unsigned long long* bits = (unsigned long long*)p;

    gat_pre<<<256 + PACKB, 256, 0, stream>>>(x, W, a, adj, hT, s1, s2, bits);
    gat_attn<<<512, 256, 0, stream>>>(bits, hT, s1, s2, out);
}

// Round 11
// 222.734 us; speedup vs baseline: 1.4630x; 1.4630x over previous
//
#include <hip/hip_runtime.h>
#include <stdint.h>

// GAT layer on MI355X: B=8, N=2048, F=128.
// h = x@W^T ; s1=h@a1 ; s2=h@a2 ; e=leaky(s1[i]+s2[j]); masked softmax; out=attn@h
// Scores rank-1. adj read exactly once (134 MB, ~21 us floor) in attn.
//
// R11: gat_h rebuilt for occupancy (R5-R9's gat_h was ~150us: 64KB LDS ->
// 2 blk/CU -> 128 CUs; W staged+converted per block). v3: 512 blocks x
// 32 rows, NO W LDS (fp32 W from L2, in-register bf16 convert), x in 16KB
// swizzled LDS, 4 blk/CU. attn = R9 verbatim (best measured structure).
//
// K1 (gat_h): wave (oh,rh) = rows[rh*16,+16) x o-half oh. Split-precision
//     x(hi+lo) MFMA, K=128. Chunked hT epilogue (HC64 swizzle in GLOBAL
//     layout -> attn staging is an identity copy). s1/s2 via shfl + LDS.
// K2 (gat_attn): 512 x 256, 2 blk/CU. b=bid&7, i0=(bid>>3)*32. Wave(jh,rh).
//     hT via global_load_lds dbuf (async, vmcnt drained by barrier).
//     adj int4 register prefetch (lane layout == A-frag). s2 from global.

#define B_ 8
#define N_ 2048
#define FD 128
#define ALPHA_ 0.2f
#define TJ 64
#define NCHL 16                   // chunks per j-half (1024/64)
#define CHUNK_U4 1024             // 128 o x 8 u4 per 64-j chunk (16 KB)

typedef __attribute__((ext_vector_type(8))) short short8;
typedef __attribute__((ext_vector_type(4))) float f32x4;

// 3-bit XOR swizzle for 128x64 hT chunks (uint4 units): row o, 16B-chunk jc(0..7)
#define HC64(o, jc) ((o) * 8 + ((jc) ^ ((o) & 7)))              // uint4 index

__device__ __forceinline__ float bf2f(unsigned short u) {
    union { uint32_t i; float f; } v; v.i = ((uint32_t)u) << 16; return v.f;
}
__device__ __forceinline__ unsigned short f2bf(float f) {
    union { float f; uint32_t i; } v; v.f = f;
    uint32_t x = v.i;
    uint32_t r = (x + 0x7fffu + ((x >> 16) & 1u)) >> 16;  // RNE
    return (unsigned short)r;
}

// async global->LDS, 16B/lane; LDS base wave-uniform, HW adds lane*16.
__device__ __forceinline__ void gl2lds16(const uint4* g, uint4* l) {
    __builtin_amdgcn_global_load_lds(
        (const __attribute__((address_space(1))) uint32_t*)g,
        (__attribute__((address_space(3))) uint32_t*)l, 16, 0, 0);
}

// ---------------------------------------------------------------------------
// Kernel 1 v3: h = x@W^T, 512 blocks x 256 thr, 32 rows/block, 4 blk/CU.
// Wave (oh=w>>1, rh=w&1): rows [rh*16,+16) local, o in [oh*64,+64) (4 ot).
// A-frag: A[m][k=quad*8+jj] = x[row][k];  B-frag: B[k][n=m] = W[o][k].
// C/D: col=lane&15 (o), row=quad*4+reg (m89/m91-verified).
// ---------------------------------------------------------------------------
__global__ __launch_bounds__(256, 4) void gat_h(
    const float* __restrict__ x,
    const float* __restrict__ W,
    const float* __restrict__ a,
    unsigned short* __restrict__ hT,   // chunked: [b][kc][HC64(o,jc)*8+(j&7)]
    float* __restrict__ s1o, float* __restrict__ s2o)
{
    __shared__ __align__(16) uint4 xs[32][32];   // 16 KB, chunk c ^ (row&31)
    __shared__ float s1c[2][32], s2c[2][32];     // o-half partials

    const int bid = blockIdx.x;
    const int tid = threadIdx.x;
    const int w = tid >> 6;
    const int lane = tid & 63;
    const int oh = w >> 1;
    const int rh = w & 1;
    const int m = lane & 15;
    const int quad = lane >> 4;

    // ---- stage x tile (32 rows x 128 f fp32 = 16 KB) coalesced ----
#pragma unroll
    for (int it = 0; it < 4; it++) {
        int idx = it * 256 + tid;          // 1024 uint4
        int row = idx >> 5, c = idx & 31;
        uint4 v = *(const uint4*)(x + (size_t)bid * 4096 + (size_t)idx * 4);
        xs[row][c ^ row] = v;
    }
    __syncthreads();

    f32x4 acc[4];
#pragma unroll
    for (int ot = 0; ot < 4; ot++) acc[ot] = (f32x4){0.f, 0.f, 0.f, 0.f};

    const int xrow = rh * 16 + m;
#pragma unroll
    for (int ks = 0; ks < 4; ks++) {
        const int c0 = ks * 8 + quad * 2;
        union { uint4 u[2]; float f[8]; } xv;
        xv.u[0] = xs[xrow][c0 ^ xrow];
        xv.u[1] = xs[xrow][(c0 + 1) ^ xrow];
        union { unsigned short us[8]; short8 v; } ahi, alo;
#pragma unroll
        for (int jj = 0; jj < 8; jj++) {
            unsigned short hi = f2bf(xv.f[jj]);
            ahi.us[jj] = hi;
            alo.us[jj] = f2bf(xv.f[jj] - bf2f(hi));
        }
#pragma unroll
        for (int ot = 0; ot < 4; ot++) {
            const int o = (oh * 4 + ot) * 16 + m;
            // W fp32 from global (L2-hot 64 KB), convert in-register
            const float* wp = W + (size_t)o * FD + ks * 32 + quad * 8;
            float4 w0 = *(const float4*)wp;
            float4 w1 = *(const float4*)(wp + 4);
            union { unsigned short us[8]; short8 v; } bw;
            bw.us[0] = f2bf(w0.x); bw.us[1] = f2bf(w0.y);
            bw.us[2] = f2bf(w0.z); bw.us[3] = f2bf(w0.w);
            bw.us[4] = f2bf(w1.x); bw.us[5] = f2bf(w1.y);
            bw.us[6] = f2bf(w1.z); bw.us[7] = f2bf(w1.w);
            acc[ot] = __builtin_amdgcn_mfma_f32_16x16x32_bf16(ahi.v, bw.v, acc[ot], 0, 0, 0);
            acc[ot] = __builtin_amdgcn_mfma_f32_16x16x32_bf16(alo.v, bw.v, acc[ot], 0, 0, 0);
        }
    }

    // ---- epilogue: chunked hT store + s1/s2 ----
    const int gr = bid * 32 + rh * 16 + quad * 4;  // C rows gr..gr+3 (= j)
    const int bb = gr >> 11;
    const int jb = gr & (N_ - 1);
    const int kc = jb >> 6;
    const int jcl = (jb & 63) >> 3;
    const int off = jb & 7;                        // 0 or 4
    unsigned short* hTb = hT + (size_t)bb * FD * N_ + (size_t)kc * (CHUNK_U4 * 8);
    float s1p[4] = {0.f, 0.f, 0.f, 0.f};
    float s2p[4] = {0.f, 0.f, 0.f, 0.f};
#pragma unroll
    for (int ot = 0; ot < 4; ot++) {
        const int o = (oh * 4 + ot) * 16 + m;
        uint2 pk;
        pk.x = (uint32_t)f2bf(acc[ot][0]) | ((uint32_t)f2bf(acc[ot][1]) << 16);
        pk.y = (uint32_t)f2bf(acc[ot][2]) | ((uint32_t)f2bf(acc[ot][3]) << 16);
        *(uint2*)(hTb + (size_t)HC64(o, jcl) * 8 + off) = pk;
        float a1v = a[o], a2v = a[FD + o];
#pragma unroll
        for (int r = 0; r < 4; r++) {
            s1p[r] += acc[ot][r] * a1v;
            s2p[r] += acc[ot][r] * a2v;
        }
    }
#pragma unroll
    for (int offx = 8; offx >= 1; offx >>= 1) {
#pragma unroll
        for (int r = 0; r < 4; r++) {
            s1p[r] += __shfl_xor(s1p[r], offx);
            s2p[r] += __shfl_xor(s2p[r], offx);
        }
    }
    if (m == 0) {
#pragma unroll
        for (int r = 0; r < 4; r++) {
            s1c[oh][rh * 16 + quad * 4 + r] = s1p[r];
            s2c[oh][rh * 16 + quad * 4 + r] = s2p[r];
        }
    }
    __syncthreads();
    if (tid < 32) {
        s1o[bid * 32 + tid] = s1c[0][tid] + s1c[1][tid];
        s2o[bid * 32 + tid] = s2c[0][tid] + s2c[1][tid];
    }
}

// ---------------------------------------------------------------------------
// Kernel 2: fused masked-softmax + PV (MFMA) — R9 verbatim.
// 512 blocks x 256 threads (4 waves), 2 blocks/CU. b = bid&7, i0=(bid>>3)*32.
// Wave w: jh = w>>1, rh = w&1: rows [i0+rh*16,+16), j [jh*1024,+1024).
// ---------------------------------------------------------------------------
__global__ __launch_bounds__(256, 2) void gat_attn(
    const int* __restrict__ adj,
    const unsigned short* __restrict__ hT,
    const float* __restrict__ s1,
    const float* __restrict__ s2,
    float* __restrict__ out)
{
    __shared__ __align__(16) uint4 hbuf[2][2][CHUNK_U4];  // [jh][buf], 64 KB

    const int bid = blockIdx.x;
    const int b = bid & 7;
    const int i0 = (bid >> 3) * 32;
    const int tid = threadIdx.x;
    const int lane = tid & 63;
    const int w = tid >> 6;
    const int jh = w >> 1;
    const int rh = w & 1;
    const int m = lane & 15;
    const int quad = lane >> 4;

    const int irow = i0 + rh * 16 + m;     // this lane's P row (A-frag m)
    const float s1v = s1[b * N_ + irow];
    const int* adjrow = adj + ((size_t)(b * N_ + irow)) * N_ + jh * 1024;
    const uint4* hTc = (const uint4*)(hT + (size_t)b * FD * N_)
                       + (size_t)jh * NCHL * CHUNK_U4;
    const float* s2b = s2 + b * N_ + jh * 1024;

    // ---- prologue: async-stage chunk 0; prefetch adj/s2 for k=0 ----
#pragma unroll
    for (int it = 0; it < 8; it++)
        gl2lds16(&hTc[it * 128 + rh * 64 + lane], &hbuf[jh][0][it * 128 + rh * 64]);
    int4 acur[4];
    float4 scur[4];
#pragma unroll
    for (int ks = 0; ks < 2; ks++) {
        acur[2 * ks]     = *(const int4*)(adjrow + ks * 32 + quad * 8);
        acur[2 * ks + 1] = *(const int4*)(adjrow + ks * 32 + quad * 8 + 4);
        scur[2 * ks]     = *(const float4*)(s2b + ks * 32 + quad * 8);
        scur[2 * ks + 1] = *(const float4*)(s2b + ks * 32 + quad * 8 + 4);
    }
    __syncthreads();

    f32x4 acc[8];
#pragma unroll
    for (int ot = 0; ot < 8; ot++) acc[ot] = (f32x4){0.f, 0.f, 0.f, 0.f};
    float rs_loc = 0.f;

    for (int k = 0; k < NCHL; k++) {
        const int buf = k & 1;
        const bool more = (k + 1 < NCHL);
        int4 anext[4];
        float4 snext[4];
        if (more) {
            // async-stage chunk k+1 (in flight across compute; barrier drains)
#pragma unroll
            for (int it = 0; it < 8; it++)
                gl2lds16(&hTc[(size_t)(k + 1) * CHUNK_U4 + it * 128 + rh * 64 + lane],
                         &hbuf[jh][buf ^ 1][it * 128 + rh * 64]);
            const int j1 = (k + 1) * TJ;
#pragma unroll
            for (int ks = 0; ks < 2; ks++) {
                anext[2 * ks]     = *(const int4*)(adjrow + j1 + ks * 32 + quad * 8);
                anext[2 * ks + 1] = *(const int4*)(adjrow + j1 + ks * 32 + quad * 8 + 4);
                snext[2 * ks]     = *(const float4*)(s2b + j1 + ks * 32 + quad * 8);
                snext[2 * ks + 1] = *(const float4*)(s2b + j1 + ks * 32 + quad * 8 + 4);
            }
        }

        // ---- compute chunk k ----
#pragma unroll
        for (int ks = 0; ks < 2; ks++) {
            float4 sa = scur[2 * ks], sb = scur[2 * ks + 1];
            float sarr[8] = {sa.x, sa.y, sa.z, sa.w, sb.x, sb.y, sb.z, sb.w};
            int4 A0 = acur[2 * ks], A1 = acur[2 * ks + 1];
            int aarr[8] = {A0.x, A0.y, A0.z, A0.w, A1.x, A1.y, A1.z, A1.w};
            union { unsigned short us[8]; short8 v; } af;
#pragma unroll
            for (int jj = 0; jj < 8; jj++) {
                float e = s1v + sarr[jj];
                e = (e > 0.f) ? e : (ALPHA_ * e);
                float p = (aarr[jj] > 0) ? __expf(e) : 0.f;
                rs_loc += p;
                af.us[jj] = f2bf(p);
            }
            const int jc = ks * 4 + quad;  // B-frag 16B-chunk index
#pragma unroll
            for (int ot = 0; ot < 8; ot++) {
                const int o = ot * 16 + m;  // B-frag n = lane&15
                union { uint4 u; short8 v; } bf;
                bf.u = *(const uint4*)&hbuf[jh][buf][HC64(o, jc)];
                acc[ot] = __builtin_amdgcn_mfma_f32_16x16x32_bf16(af.v, bf.v, acc[ot], 0, 0, 0);
            }
        }

        __syncthreads();  // drains vmcnt(0): chunk k+1 staged; safe to flip
        if (more) {
#pragma unroll
            for (int q = 0; q < 4; q++) { acur[q] = anext[q]; scur[q] = snext[q]; }
        }
    }

    // ---- cross-j-half combine via LDS (reuse hbuf; last barrier above) ----
    float* xch = (float*)&hbuf[0][0][0];   // 16 KB acc + 128 B rowsums
    rs_loc += __shfl_xor(rs_loc, 16);      // all lanes: sum for row m
    rs_loc += __shfl_xor(rs_loc, 32);
    if (jh == 1) {
#pragma unroll
        for (int ot = 0; ot < 8; ot++)
#pragma unroll
            for (int r = 0; r < 4; r++)
                xch[rh * 2048 + (quad * 4 + r) * 128 + ot * 16 + m] = acc[ot][r];
        if (quad == 0) xch[4096 + rh * 16 + m] = rs_loc;
    }
    __syncthreads();
    if (jh == 0) {
        float rinv[4];
#pragma unroll
        for (int r = 0; r < 4; r++) {
            const int p = quad * 4 + r;
            rinv[r] = 1.0f / (__shfl(rs_loc, p) + xch[4096 + rh * 16 + p]);
        }
        float* outp = out + (size_t)(b * N_ + i0 + rh * 16) * FD;
#pragma unroll
        for (int ot = 0; ot < 8; ot++) {
            const int col = ot * 16 + m;
#pragma unroll
            for (int r = 0; r < 4; r++) {
                float v = acc[ot][r] + xch[rh * 2048 + (quad * 4 + r) * 128 + col];
                outp[(size_t)(quad * 4 + r) * FD + col] = v * rinv[r];
            }
        }
    }
}

// ---------------------------------------------------------------------------
extern "C" void kernel_launch(void* const* d_in, const int* in_sizes, int n_in,
                              void* d_out, int out_size, void* d_ws, size_t ws_size,
                              hipStream_t stream) {
    const void* xv = d_in[0];
    const void* adjv = d_in[1];
    const void* Wv = d_in[2];
    const void* av = d_in[3];
    for (int i = 0; i < n_in; i++) {
        switch (in_sizes[i]) {
            case 2097152:  xv = d_in[i]; break;
            case 33554432: adjv = d_in[i]; break;
            case 16384:    Wv = d_in[i]; break;
            case 256:      av = d_in[i]; break;
            default: break;
        }
    }
    const float* x = (const float*)xv;
    const int* adj = (const int*)adjv;
    const float* W = (const float*)Wv;
    const float* a = (const float*)av;
    float* out = (float*)d_out;

    // ws: hT 4MB | s1 64KB | s2 64KB
    char* p = (char*)d_ws;
    unsigned short* hT = (unsigned short*)p;  p += (size_t)B_ * FD * N_ * 2;
    float* s1 = (float*)p;                    p += (size_t)B_ * N_ * 4;
    float* s2 = (float*)p;

    gat_h<<<512, 256, 0, stream>>>(x, W, a, hT, s1, s2);
    gat_attn<<<512, 256, 0, stream>>>(adj, hT, s1, s2, out);
}